// Round 14
// baseline (325.193 us; speedup 1.0000x reference)
//
#include <hip/hip_runtime.h>
#include <hip/hip_bf16.h>

#define HC    256
#define FIN   32
#define NH    8
#define GROUP 8     // dst nodes per block (2 per wave)
#define CAPW  32    // per-wave staged edges per chunk

typedef __hip_bfloat16 bf16;

__device__ __forceinline__ float blo(unsigned int u) { return __uint_as_float(u << 16); }
__device__ __forceinline__ float bhi(unsigned int u) { return __uint_as_float(u & 0xffff0000u); }
__device__ __forceinline__ unsigned int pk2(float a, float b) {
  bf16 ha = __float2bfloat16(a), hb = __float2bfloat16(b);
  unsigned short ua, ub;
  __builtin_memcpy(&ua, &ha, 2); __builtin_memcpy(&ub, &hb, 2);
  return (unsigned int)ua | ((unsigned int)ub << 16);
}
__device__ __forceinline__ short bfs(float v) {
  bf16 h = __float2bfloat16(v);
  short s; __builtin_memcpy(&s, &h, 2);
  return s;
}

// ---------------- CSR build ---------------------------------------------------
// blocks [0,eb): count + per-edge rank (coalesced ord write).
// block eb: folded weight prep + fragment-ordered bf16 W AND Wlin for the
// MFMA epilogues (B-frag: lane l holds B[k=(l>>4)*8+j][col=l&15]; verified
// numerically R10-R12, absmax unchanged).
// wfrag  : [tile=hh*2+n2][lane][j],  value W[(seg*8+j)*HC + hh*32+n2*16+row]
// wlinf1 : [tl=(ct*4+w)*2+step][lane][j], value lin1W[(w*64+step*32+seg*8+j)*32 + ct*16+row]
// wlinf2 : [tl=w*2+step][lane][j], value lin5W[(w*64+step*32+seg*8+j)*8 + row] (row>=8 -> 0)
__global__ void count_fold_kernel(const int* __restrict__ dst, int* __restrict__ cnt,
                                  int* __restrict__ ord, int E_, int eb,
                                  const float* __restrict__ We1, const float* __restrict__ ae1,
                                  const float* __restrict__ We2, const float* __restrict__ ae2,
                                  const float* __restrict__ W1, const float* __restrict__ as1,
                                  const float* __restrict__ ad1,
                                  const float* __restrict__ W2, const float* __restrict__ as2,
                                  const float* __restrict__ ad2,
                                  const float* __restrict__ lin1W,
                                  const float* __restrict__ lin5W,
                                  float* __restrict__ M,
                                  bf16* __restrict__ w1frag, bf16* __restrict__ w2frag,
                                  bf16* __restrict__ w1linf, bf16* __restrict__ w2linf) {
  if (blockIdx.x < (unsigned)eb) {
    int e = blockIdx.x * blockDim.x + threadIdx.x;
    if (e < E_) ord[e] = atomicAdd(&cnt[dst[e]], 1);
  } else {
    for (int idx = threadIdx.x; idx < 1152; idx += 256) {
      const float* A; const float* V; int i;
      if (idx < 64)       { i = idx;       A = We1; V = ae1; }
      else if (idx < 128) { i = idx - 64;  A = We2; V = ae2; }
      else if (idx < 384) { i = idx - 128; A = W1;  V = as1; }
      else if (idx < 640) { i = idx - 384; A = W1;  V = ad1; }
      else if (idx < 896) { i = idx - 640; A = W2;  V = as2; }
      else                { i = idx - 896; A = W2;  V = ad2; }
      int k = i >> 3, h = i & 7;
      float s = 0.f;
      for (int c = 0; c < FIN; ++c)
        s = fmaf(A[k * HC + h * FIN + c], V[h * FIN + c], s);
      M[idx] = s;
    }
    // fragment-ordered bf16 W1/W2 (16 tiles x 64 lanes x 8)
    for (int idx = threadIdx.x; idx < 8192; idx += 256) {
      int j = idx & 7, lane = (idx >> 3) & 63, tile = idx >> 9;
      int seg = lane >> 4, row = lane & 15;
      int hh = tile >> 1, n2 = tile & 1;
      int k = seg * 8 + j, col = hh * 32 + n2 * 16 + row;
      w1frag[idx] = __float2bfloat16(W1[k * HC + col]);
      w2frag[idx] = __float2bfloat16(W2[k * HC + col]);
    }
    // fragment-ordered bf16 lin1W (16 tiles)
    for (int idx = threadIdx.x; idx < 8192; idx += 256) {
      int j = idx & 7, lane = (idx >> 3) & 63, tl = idx >> 9;
      int seg = lane >> 4, row = lane & 15;
      int ct = tl >> 3, w_ = (tl >> 1) & 3, step = tl & 1;
      int krow = w_ * 64 + step * 32 + seg * 8 + j;
      w1linf[idx] = __float2bfloat16(lin1W[krow * 32 + ct * 16 + row]);
    }
    // fragment-ordered bf16 lin5W (8 tiles, cols 8..15 zero-padded)
    for (int idx = threadIdx.x; idx < 4096; idx += 256) {
      int j = idx & 7, lane = (idx >> 3) & 63, tl = idx >> 9;
      int seg = lane >> 4, row = lane & 15;
      int w_ = tl >> 1, step = tl & 1;
      int krow = w_ * 64 + step * 32 + seg * 8 + j;
      w2linf[idx] = (row < 8) ? __float2bfloat16(lin5W[krow * 8 + row])
                              : __float2bfloat16(0.f);
    }
  }
}

// scan step 1: per-256-tile inclusive prefix (into tmp) + raw tile sums (bsum)
__global__ __launch_bounds__(256) void
scan_partial(const int* __restrict__ cnt, int* __restrict__ tmp,
             int* __restrict__ bsum, int N_) {
  __shared__ int part[256];
  int t = threadIdx.x, i = blockIdx.x * 256 + t;
  int v = (i < N_) ? cnt[i] : 0;
  part[t] = v;
  __syncthreads();
#pragma unroll
  for (int off = 1; off < 256; off <<= 1) {
    int u = (t >= off) ? part[t - off] : 0;
    __syncthreads();
    part[t] += u;
    __syncthreads();
  }
  if (i < N_) tmp[i] = part[t];
  if (t == 255) bsum[blockIdx.x] = part[255];
}

// scan step 2 (fused): each block reduces bsum[0..bid) itself, then
// rowptr[i] = boff + incl[i] - cnt[i]; rowptr[N]=E.
__global__ __launch_bounds__(256) void
scan_final(const int* __restrict__ cnt, const int* __restrict__ tmp,
           const int* __restrict__ bsum, int* __restrict__ rowptr,
           int N_, int E_, int NB) {
  __shared__ int red[256];
  int t = threadIdx.x, b = blockIdx.x;
  int acc = 0;
  for (int j = t; j < b; j += 256) acc += bsum[j];
  red[t] = acc;
  __syncthreads();
#pragma unroll
  for (int off = 128; off > 0; off >>= 1) {
    if (t < off) red[t] += red[t + off];
    __syncthreads();
  }
  int boff = red[0];
  int i = b * 256 + t;
  if (i < N_) rowptr[i] = boff + tmp[i] - cnt[i];
  if (i == 0) rowptr[N_] = E_;
}

// scatter-lite (no atomics, ONE 8B scattered write/edge) + fused layer-1 prep.
__global__ __launch_bounds__(256) void
scatter_prep_kernel(const int* __restrict__ src, const int* __restrict__ dst,
                    const int* __restrict__ rowptr, const int* __restrict__ ord,
                    int2* __restrict__ se,
                    const float* __restrict__ M,
                    const float* __restrict__ emb, const int* __restrict__ node_ids,
                    bf16* __restrict__ xq, float* __restrict__ alsrc,
                    float* __restrict__ aldst,
                    int E_, int N_, int eb) {
  __shared__ float xs[8][33];
  int t = threadIdx.x;
  if (blockIdx.x < (unsigned)eb) {
    int e = blockIdx.x * 256 + t;
    if (e < E_) {
      int pos = rowptr[dst[e]] + ord[e];
      se[pos] = make_int2(src[e], e);   // single 8B scattered write
    }
  } else {
    const float* P = M + 128;
    int n0 = (blockIdx.x - eb) * 8;
    int nl = t >> 5, c = t & 31;
    int n = n0 + nl;
    if (n < N_) {
      float v = emb[(size_t)node_ids[n] * FIN + c];
      xq[(size_t)n * FIN + c] = __float2bfloat16(v);
      xs[nl][c] = v;
    }
    __syncthreads();
    if (t < 64) {
      int nl2 = t >> 3, h = t & 7;
      int n2 = n0 + nl2;
      if (n2 < N_) {
        float sa = 0.f, sd = 0.f;
#pragma unroll
        for (int k = 0; k < FIN; ++k) {
          float x = xs[nl2][k];
          sa = fmaf(x, P[k * 8 + h], sa);
          sd = fmaf(x, P[256 + k * 8 + h], sd);
        }
        alsrc[(size_t)n2 * NH + h] = sa;
        aldst[(size_t)n2 * NH + h] = sd;
      }
    }
  }
}

// pos-order pass: gather edge_attr[e] ONCE (random), fold with M, write
// srcs + per-layer packed bf16 records COALESCED (16B each layer).
__global__ __launch_bounds__(256) void
alepk_build_kernel(const int2* __restrict__ se, const float* __restrict__ edge_attr,
                   const float* __restrict__ M,
                   int* __restrict__ srcs, unsigned int* __restrict__ ale1pk,
                   unsigned int* __restrict__ ale2pk, int E_) {
  __shared__ float Msh[128];
  int t = threadIdx.x;
  if (t < 128) Msh[t] = M[t];
  __syncthreads();
  int pos = blockIdx.x * 256 + t;
  if (pos >= E_) return;
  int2 s2 = se[pos];
  srcs[pos] = s2.x;
  int e = s2.y;
  const float4* ep = (const float4*)(edge_attr + (size_t)e * NH);
  float4 a0 = ep[0], a1 = ep[1];
  float ea[8] = {a0.x, a0.y, a0.z, a0.w, a1.x, a1.y, a1.z, a1.w};
  float o1[8], o2[8];
#pragma unroll
  for (int h = 0; h < 8; ++h) { o1[h] = 0.f; o2[h] = 0.f; }
#pragma unroll
  for (int k = 0; k < 8; ++k) {
    float x = ea[k];
#pragma unroll
    for (int h = 0; h < 8; ++h) {
      o1[h] = fmaf(x, Msh[k * 8 + h], o1[h]);
      o2[h] = fmaf(x, Msh[64 + k * 8 + h], o2[h]);
    }
  }
  uint4 r0 = make_uint4(pk2(o1[0], o1[1]), pk2(o1[2], o1[3]),
                        pk2(o1[4], o1[5]), pk2(o1[6], o1[7]));
  uint4 r1 = make_uint4(pk2(o2[0], o2[1]), pk2(o2[2], o2[3]),
                        pk2(o2[4], o2[5]), pk2(o2[6], o2[7]));
  *(uint4*)(ale1pk + (size_t)pos * 4) = r0;
  *(uint4*)(ale2pk + (size_t)pos * 4) = r1;
}

// ---- fused agg: BARRIER-FREE main loop + double-MFMA epilogue ---------------
// Main loop identical to verified R7/R12. Epilogue:
//   (a) z@W via mfma_f32_16x16x32_bf16 (verified), gs stored XOR-swizzled.
//   (b) lin via MFMA: wave w k-slice = channels [64w,64w+64) (its OWN gs cols),
//       4 (LOGITS) / 2 MFMA per wave, partials 4-way reduced in LDS `red`.
// LDS: z swz [0,8K) -> red [0,8K) (z dead) | gs swz [8K,16K) | ald_s 12288..
//      (ald_s at 12288 only used in main loop, before gs is written) | xrow 16384.
template <int K, int LOG2K, bool LOGITS>
__global__ __launch_bounds__(256, 6) void
agg_kernel(const int* __restrict__ rowptr, const int* __restrict__ srcs,
           const bf16* __restrict__ ale,
           const float* __restrict__ alsrc, const float* __restrict__ aldst,
           const bf16* __restrict__ xq,
           const bf16* __restrict__ Wfrag, const float* __restrict__ b,
           const bf16* __restrict__ Wlinf, const float* __restrict__ blin,
           float* __restrict__ xoutf, bf16* __restrict__ xqn,
           const float* __restrict__ Pn,
           float* __restrict__ alsrcn, float* __restrict__ aldstn, int N_) {
  __shared__ __align__(16) char smem[17408];
  unsigned int* xsu = (unsigned int*)smem;
  float* wsf   = (float*)(smem + 8192);
  float* ald_s = (float*)(smem + 12288);
  float* red   = (float*)smem;
  float* xrow  = (float*)(smem + 16384);

  int t = threadIdx.x;
  int n0 = blockIdx.x * GROUP;
  int w = t >> 6, l = t & 63, h = l >> 3, q = l & 7;

  unsigned int* xw  = xsu + w * 512;
  float*        wsw = wsf + w * 256;
  char* xwb = smem + w * 2048;

  int nA = n0 + w * 2;
  int e0  = rowptr[(nA     <= N_) ? nA     : N_];
  int e1  = rowptr[(nA + 1 <= N_) ? nA + 1 : N_];
  int e2g = rowptr[(nA + 2 <= N_) ? nA + 2 : N_];

  if (t < GROUP * NH) {
    int nn = n0 + (t >> 3);
    ald_s[t] = (nn < N_) ? aldst[(size_t)nn * NH + (t & 7)] : 0.f;
  }
  __syncthreads();

  float4 acc0 = make_float4(0.f, 0.f, 0.f, 0.f);
  float4 acc1 = make_float4(0.f, 0.f, 0.f, 0.f);
  float dn0 = 0.f, dn1 = 0.f;

  for (int cbeg = e0; cbeg < e2g; cbeg += CAPW) {
    int clen = e2g - cbeg; if (clen > CAPW) clen = CAPW;

    // stage x rows: 2 passes of 16 edges via global_load_lds (16B/lane)
    {
      int el0 = (l >> 2);
      int coff = (l & 3);
      int ec0 = el0 < clen - 1 ? el0 : clen - 1;
      {
        int s = srcs[cbeg + ec0];
        const bf16* gp = xq + (size_t)s * FIN + coff * 8;
        __builtin_amdgcn_global_load_lds(
            (const __attribute__((address_space(1))) void*)gp,
            (__attribute__((address_space(3))) void*)xwb, 16, 0, 0);
      }
      if (clen > 16) {
        int el1 = 16 + el0;
        int ec1 = el1 < clen - 1 ? el1 : clen - 1;
        int s = srcs[cbeg + ec1];
        const bf16* gp = xq + (size_t)s * FIN + coff * 8;
        __builtin_amdgcn_global_load_lds(
            (const __attribute__((address_space(1))) void*)gp,
            (__attribute__((address_space(3))) void*)(xwb + 1024), 16, 0, 0);
      }
    }
    // stage exp(alpha): 2 lanes/edge
    {
      int e2 = l >> 1, half = l & 1;
      if (e2 < clen) {
        int j = cbeg + e2;
        int ii = (j >= e1) ? 1 : 0;
        int sn = srcs[j];
        uint2 ue  = *(const uint2*)(ale + (size_t)j * 8 + half * 4);
        float4 as4 = *(const float4*)(alsrc + (size_t)sn * NH + half * 4);
        float4 ad4 = *(const float4*)&ald_s[(w * 2 + ii) * 8 + half * 4];
        float a0f = blo(ue.x) + as4.x + ad4.x; a0f = (a0f >= 0.f) ? a0f : 0.2f * a0f;
        float a1f = bhi(ue.x) + as4.y + ad4.y; a1f = (a1f >= 0.f) ? a1f : 0.2f * a1f;
        float a2f = blo(ue.y) + as4.z + ad4.z; a2f = (a2f >= 0.f) ? a2f : 0.2f * a2f;
        float a3f = bhi(ue.y) + as4.w + ad4.w; a3f = (a3f >= 0.f) ? a3f : 0.2f * a3f;
        *(float4*)&wsw[e2 * 8 + half * 4] =
            make_float4(__expf(a0f), __expf(a1f), __expf(a2f), __expf(a3f));
      }
    }
    asm volatile("s_waitcnt vmcnt(0) lgkmcnt(0)" ::: "memory");

    int hA = e1 - cbeg; if (hA < 0) hA = 0; if (hA > clen) hA = clen;
#pragma unroll 4
    for (int le = 0; le < hA; ++le) {
      float wv = wsw[le * 8 + h];
      uint2 u = *(const uint2*)&xw[le * 16 + q * 2];
      acc0.x = fmaf(blo(u.x), wv, acc0.x);
      acc0.y = fmaf(bhi(u.x), wv, acc0.y);
      acc0.z = fmaf(blo(u.y), wv, acc0.z);
      acc0.w = fmaf(bhi(u.y), wv, acc0.w);
      dn0 += wv;
    }
#pragma unroll 4
    for (int le = hA; le < clen; ++le) {
      float wv = wsw[le * 8 + h];
      uint2 u = *(const uint2*)&xw[le * 16 + q * 2];
      acc1.x = fmaf(blo(u.x), wv, acc1.x);
      acc1.y = fmaf(bhi(u.x), wv, acc1.y);
      acc1.z = fmaf(blo(u.y), wv, acc1.z);
      acc1.w = fmaf(bhi(u.y), wv, acc1.w);
      dn1 += wv;
    }
    asm volatile("s_waitcnt lgkmcnt(0)" ::: "memory");
  }

  // normalize + write z XOR-swizzled (float4 #f of node n at n*1024+((f^n)&63)*16)
  float rd0 = 1.0f / (dn0 + 1e-16f);
  float rd1 = 1.0f / (dn1 + 1e-16f);
  {
    int na0 = w * 2, na1 = w * 2 + 1;
    *(float4*)(smem + na0 * 1024 + ((l ^ na0) & 63) * 16) =
        make_float4(acc0.x * rd0, acc0.y * rd0, acc0.z * rd0, acc0.w * rd0);
    *(float4*)(smem + na1 * 1024 + ((l ^ na1) & 63) * 16) =
        make_float4(acc1.x * rd1, acc1.y * rd1, acc1.z * rd1, acc1.w * rd1);
  }
  __syncthreads();

  typedef __attribute__((ext_vector_type(8))) short short8v;
  typedef __attribute__((ext_vector_type(4))) float f32x4v;
  int lo = l & 15, seg = l >> 4;

  // (a) g = relu(z @ W + b) via MFMA; gs stored swizzled at smem+8192
  {
#pragma unroll
    for (int hh2 = 0; hh2 < 2; ++hh2) {
      int hh = w * 2 + hh2;
      short8v af;
      if (lo < GROUP) {
        int f0 = hh * 8 + seg * 2;
        float4 za = *(const float4*)(smem + lo * 1024 + ((f0 ^ lo) & 63) * 16);
        float4 zb = *(const float4*)(smem + lo * 1024 + (((f0 + 1) ^ lo) & 63) * 16);
        af[0] = bfs(za.x); af[1] = bfs(za.y); af[2] = bfs(za.z); af[3] = bfs(za.w);
        af[4] = bfs(zb.x); af[5] = bfs(zb.y); af[6] = bfs(zb.z); af[7] = bfs(zb.w);
      } else {
#pragma unroll
        for (int j = 0; j < 8; ++j) af[j] = 0;
      }
#pragma unroll
      for (int n2 = 0; n2 < 2; ++n2) {
        int tile = hh * 2 + n2;
        uint4 bw = *(const uint4*)(Wfrag + (size_t)tile * 512 + l * 8);
        short8v bfv;
        __builtin_memcpy(&bfv, &bw, 16);
        f32x4v d = {0.f, 0.f, 0.f, 0.f};
        d = __builtin_amdgcn_mfma_f32_16x16x32_bf16(af, bfv, d, 0, 0, 0);
#pragma unroll
        for (int r = 0; r < 4; ++r) {
          int rd = seg * 4 + r;
          if (rd < GROUP) {
            int tc = hh * 32 + n2 * 16 + lo;
            float gv = d[r] + b[tc];
            gv = (gv > 0.f) ? gv : 0.f;
            *(float*)(smem + 8192 + rd * 1024 +
                      (((tc >> 2) ^ rd) & 63) * 16 + (tc & 3) * 4) = gv;
          }
        }
      }
    }
  }
  __syncthreads();   // all z reads done -> red (aliases z) safe; gs wave-local

  // (b) lin via MFMA: wave w k-slice [64w,64w+64) (its own gs cols)
  {
    short8v af0, af1;
    if (lo < GROUP) {
      int f0 = 16 * w + 2 * seg;          // k-step 0, float4 index of channel base
      float4 ga = *(const float4*)(smem + 8192 + lo * 1024 + ((f0 ^ lo) & 63) * 16);
      float4 gb = *(const float4*)(smem + 8192 + lo * 1024 + (((f0 + 1) ^ lo) & 63) * 16);
      int f1 = 16 * w + 8 + 2 * seg;      // k-step 1
      float4 gc = *(const float4*)(smem + 8192 + lo * 1024 + ((f1 ^ lo) & 63) * 16);
      float4 gd = *(const float4*)(smem + 8192 + lo * 1024 + (((f1 + 1) ^ lo) & 63) * 16);
      af0[0] = bfs(ga.x); af0[1] = bfs(ga.y); af0[2] = bfs(ga.z); af0[3] = bfs(ga.w);
      af0[4] = bfs(gb.x); af0[5] = bfs(gb.y); af0[6] = bfs(gb.z); af0[7] = bfs(gb.w);
      af1[0] = bfs(gc.x); af1[1] = bfs(gc.y); af1[2] = bfs(gc.z); af1[3] = bfs(gc.w);
      af1[4] = bfs(gd.x); af1[5] = bfs(gd.y); af1[6] = bfs(gd.z); af1[7] = bfs(gd.w);
    } else {
#pragma unroll
      for (int j = 0; j < 8; ++j) { af0[j] = 0; af1[j] = 0; }
    }
#pragma unroll
    for (int ct = 0; ct < (LOGITS ? 2 : 1); ++ct) {
      int tl = LOGITS ? ((ct * 4 + w) * 2) : (w * 2);
      uint4 b0 = *(const uint4*)(Wlinf + (size_t)tl * 512 + l * 8);
      uint4 b1 = *(const uint4*)(Wlinf + (size_t)(tl + 1) * 512 + l * 8);
      short8v bv0, bv1;
      __builtin_memcpy(&bv0, &b0, 16);
      __builtin_memcpy(&bv1, &b1, 16);
      f32x4v d = {0.f, 0.f, 0.f, 0.f};
      d = __builtin_amdgcn_mfma_f32_16x16x32_bf16(af0, bv0, d, 0, 0, 0);
      d = __builtin_amdgcn_mfma_f32_16x16x32_bf16(af1, bv1, d, 0, 0, 0);
      int base = (LOGITS ? (ct * 4 + w) : w) * 256;
#pragma unroll
      for (int r = 0; r < 4; ++r)
        red[base + (seg * 4 + r) * 16 + lo] = d[r];
    }
  }
  __syncthreads();

  // combine partials (+blin) -> outputs
  if (LOGITS) {
    {
      int i = t >> 5, kk = t & 31;
      int ct = kk >> 4, n = kk & 15;
      float s = blin[kk]
              + red[(ct * 4 + 0) * 256 + i * 16 + n]
              + red[(ct * 4 + 1) * 256 + i * 16 + n]
              + red[(ct * 4 + 2) * 256 + i * 16 + n]
              + red[(ct * 4 + 3) * 256 + i * 16 + n];
      int nn = n0 + i;
      if (nn < N_) xqn[(size_t)nn * FIN + kk] = __float2bfloat16(s);
      xrow[t] = s;
    }
    __syncthreads();
    if (t < GROUP * NH) {
      int i = t >> 3, hh = t & 7;
      int nn = n0 + i;
      if (nn < N_) {
        float sa = 0.f, sd = 0.f;
#pragma unroll
        for (int k2 = 0; k2 < FIN; ++k2) {
          float x = xrow[i * 32 + k2];
          sa = fmaf(x, Pn[k2 * 8 + hh], sa);
          sd = fmaf(x, Pn[256 + k2 * 8 + hh], sd);
        }
        alsrcn[(size_t)nn * NH + hh] = sa;
        aldstn[(size_t)nn * NH + hh] = sd;
      }
    }
  } else {
    if (t < GROUP * K) {
      int i = t >> LOG2K, kk = t & (K - 1);
      float s = blin[kk]
              + red[0 * 256 + i * 16 + kk]
              + red[1 * 256 + i * 16 + kk]
              + red[2 * 256 + i * 16 + kk]
              + red[3 * 256 + i * 16 + kk];
      int nn = n0 + i;
      if (nn < N_) xoutf[(size_t)nn * K + kk] = s;
    }
  }
}

// ---------------- classifier: sigmoid(sum(fu*fm)) ----------------------------
__global__ void clf_kernel(const int* __restrict__ eli, const float* __restrict__ ela,
                           const float* __restrict__ x2, const float* __restrict__ clfW,
                           const float* __restrict__ clfb, float* __restrict__ out, int L_) {
  int i = blockIdx.x * blockDim.x + threadIdx.x;
  if (i >= L_) return;
  int u = eli[i], m = eli[L_ + i];
  const float4* xup = (const float4*)(x2 + (size_t)u * NH);
  const float4* xmp = (const float4*)(x2 + (size_t)m * NH);
  const float4* eap = (const float4*)(ela + (size_t)i * NH);
  float4 xu0 = xup[0], xu1 = xup[1];
  float4 xm0 = xmp[0], xm1 = xmp[1];
  float4 el0 = eap[0], el1 = eap[1];
  float xu[NH] = {xu0.x, xu0.y, xu0.z, xu0.w, xu1.x, xu1.y, xu1.z, xu1.w};
  float xm[NH] = {xm0.x, xm0.y, xm0.z, xm0.w, xm1.x, xm1.y, xm1.z, xm1.w};
  float el[NH] = {el0.x, el0.y, el0.z, el0.w, el1.x, el1.y, el1.z, el1.w};
  float fu[NH];
#pragma unroll
  for (int kk = 0; kk < NH; ++kk) fu[kk] = clfb[kk];
#pragma unroll
  for (int j = 0; j < NH; ++j) {
#pragma unroll
    for (int kk = 0; kk < NH; ++kk) fu[kk] = fmaf(xu[j], clfW[j * NH + kk], fu[kk]);
  }
#pragma unroll
  for (int j = 0; j < NH; ++j) {
#pragma unroll
    for (int kk = 0; kk < NH; ++kk) fu[kk] = fmaf(el[j], clfW[(NH + j) * NH + kk], fu[kk]);
  }
  float dot = 0.f;
#pragma unroll
  for (int kk = 0; kk < NH; ++kk) dot += fu[kk] * xm[kk];
  out[i] = 1.f / (1.f + __expf(-dot));
}

extern "C" void kernel_launch(void* const* d_in, const int* in_sizes, int n_in,
                              void* d_out, int out_size, void* d_ws, size_t ws_size,
                              hipStream_t stream) {
  const int* node_ids   = (const int*)d_in[0];
  const int* edge_index = (const int*)d_in[1];
  const int* eli        = (const int*)d_in[2];
  const float* edge_attr = (const float*)d_in[4];
  const float* ela       = (const float*)d_in[5];
  const float* emb       = (const float*)d_in[6];
  const float* W1     = (const float*)d_in[7];
  const float* a_src1 = (const float*)d_in[8];
  const float* a_dst1 = (const float*)d_in[9];
  const float* We1    = (const float*)d_in[10];
  const float* a_e1   = (const float*)d_in[11];
  const float* b1     = (const float*)d_in[12];
  const float* lin1W  = (const float*)d_in[13];
  const float* lin1b  = (const float*)d_in[14];
  const float* W2     = (const float*)d_in[15];
  const float* a_src2 = (const float*)d_in[16];
  const float* a_dst2 = (const float*)d_in[17];
  const float* We2    = (const float*)d_in[18];
  const float* a_e2   = (const float*)d_in[19];
  const float* b2     = (const float*)d_in[20];
  const float* lin5W  = (const float*)d_in[21];
  const float* lin5b  = (const float*)d_in[22];
  const float* clfW   = (const float*)d_in[23];
  const float* clfb   = (const float*)d_in[24];

  const int N_ = in_sizes[0];
  const int E_ = in_sizes[1] / 2;
  const int L_ = in_sizes[2] / 2;
  const int* src  = edge_index;
  const int* dstp = edge_index + E_;

  char* p = (char*)d_ws;
  auto carve = [&](size_t bytes) -> char* {
    char* r = p;
    p += (bytes + 255) & ~(size_t)255;
    return r;
  };
  bf16*  xq1     = (bf16*)carve((size_t)N_ * FIN * 2);
  bf16*  xq2     = (bf16*)carve((size_t)N_ * FIN * 2);
  unsigned int* ale1pk = (unsigned int*)carve((size_t)E_ * 16);
  unsigned int* ale2pk = (unsigned int*)carve((size_t)E_ * 16);
  float* alsrc1  = (float*)carve((size_t)N_ * NH * 4);
  float* aldst1  = (float*)carve((size_t)N_ * NH * 4);
  float* alsrc2  = (float*)carve((size_t)N_ * NH * 4);
  float* aldst2  = (float*)carve((size_t)N_ * NH * 4);
  float* x2b     = (float*)carve((size_t)N_ * NH * 4);
  float* Mbuf    = (float*)carve(1152 * 4);
  bf16*  w1frag  = (bf16*)carve(8192 * 2);
  bf16*  w2frag  = (bf16*)carve(8192 * 2);
  bf16*  w1linf  = (bf16*)carve(8192 * 2);
  bf16*  w2linf  = (bf16*)carve(4096 * 2);
  int*   cnt     = (int*)carve((size_t)N_ * 4);
  int*   rowptr  = (int*)carve((size_t)(N_ + 1) * 4);
  int*   stmp    = (int*)carve((size_t)N_ * 4);
  int*   bsum    = (int*)carve(1024 * 4);
  int*   srcs    = (int*)carve((size_t)E_ * 4);
  int*   ordb    = (int*)carve((size_t)E_ * 4);
  int2*  se      = (int2*)carve((size_t)E_ * 8);

  hipMemsetAsync(cnt, 0, (size_t)N_ * 4, stream);
  int eb = (E_ + 255) / 256;
  int nb = (N_ + 255) / 256;
  int pb = (N_ + 7) / 8;
  count_fold_kernel<<<eb + 1, 256, 0, stream>>>(dstp, cnt, ordb, E_, eb,
                                                We1, a_e1, We2, a_e2,
                                                W1, a_src1, a_dst1,
                                                W2, a_src2, a_dst2,
                                                lin1W, lin5W, Mbuf,
                                                w1frag, w2frag, w1linf, w2linf);
  scan_partial<<<nb, 256, 0, stream>>>(cnt, stmp, bsum, N_);
  scan_final<<<nb, 256, 0, stream>>>(cnt, stmp, bsum, rowptr, N_, E_, nb);
  scatter_prep_kernel<<<eb + pb, 256, 0, stream>>>(
      src, dstp, rowptr, ordb, se, Mbuf,
      emb, node_ids, xq1, alsrc1, aldst1, E_, N_, eb);
  alepk_build_kernel<<<eb, 256, 0, stream>>>(se, edge_attr, Mbuf, srcs,
                                             ale1pk, ale2pk, E_);

  int gb = (N_ + GROUP - 1) / GROUP;
  // ---- layer 1 (fully fused) ----
  agg_kernel<32, 5, true><<<gb, 256, 0, stream>>>(
      rowptr, srcs, (const bf16*)ale1pk, alsrc1, aldst1, xq1,
      w1frag, b1, w1linf, lin1b, nullptr, xq2, Mbuf + 640, alsrc2, aldst2, N_);

  // ---- layer 2 ----
  agg_kernel<8, 3, false><<<gb, 256, 0, stream>>>(
      rowptr, srcs, (const bf16*)ale2pk, alsrc2, aldst2, xq2,
      w2frag, b2, w2linf, lin5b, x2b, nullptr, nullptr, nullptr, nullptr, N_);

  // ---- classifier ----
  clf_kernel<<<(L_ + 255) / 256, 256, 0, stream>>>(eli, ela, x2b, clfW, clfb,
                                                   (float*)d_out, L_);
}

// Round 15
// 317.328 us; speedup vs baseline: 1.0248x; 1.0248x over previous
//
#include <hip/hip_runtime.h>
#include <hip/hip_bf16.h>

#define HC    256
#define FIN   32
#define NH    8
#define GROUP 8     // dst nodes per block (2 per wave)
#define CAPW  32    // per-wave staged edges per chunk
#define NSH   4     // count shadow arrays (atomic contention split)

typedef __hip_bfloat16 bf16;

__device__ __forceinline__ float blo(unsigned int u) { return __uint_as_float(u << 16); }
__device__ __forceinline__ float bhi(unsigned int u) { return __uint_as_float(u & 0xffff0000u); }
__device__ __forceinline__ unsigned int pk2(float a, float b) {
  bf16 ha = __float2bfloat16(a), hb = __float2bfloat16(b);
  unsigned short ua, ub;
  __builtin_memcpy(&ua, &ha, 2); __builtin_memcpy(&ub, &hb, 2);
  return (unsigned int)ua | ((unsigned int)ub << 16);
}
__device__ __forceinline__ short bfs(float v) {
  bf16 h = __float2bfloat16(v);
  short s; __builtin_memcpy(&s, &h, 2);
  return s;
}

// ---------------- CSR build ---------------------------------------------------
// blocks [0,eb): shadow-split count (s = e&3) + per-edge shadow-rank (ordp).
// block eb: folded weight prep + fragment-ordered bf16 W / Wlin (verified
// layouts, R10-R14: absmax unchanged).
__global__ void count_fold_kernel(const int* __restrict__ dst, int* __restrict__ cnt4,
                                  int* __restrict__ ord, int E_, int N_, int eb,
                                  const float* __restrict__ We1, const float* __restrict__ ae1,
                                  const float* __restrict__ We2, const float* __restrict__ ae2,
                                  const float* __restrict__ W1, const float* __restrict__ as1,
                                  const float* __restrict__ ad1,
                                  const float* __restrict__ W2, const float* __restrict__ as2,
                                  const float* __restrict__ ad2,
                                  const float* __restrict__ lin1W,
                                  const float* __restrict__ lin5W,
                                  float* __restrict__ M,
                                  bf16* __restrict__ w1frag, bf16* __restrict__ w2frag,
                                  bf16* __restrict__ w1linf, bf16* __restrict__ w2linf) {
  if (blockIdx.x < (unsigned)eb) {
    int e = blockIdx.x * blockDim.x + threadIdx.x;
    if (e < E_) {
      int s = e & (NSH - 1);
      ord[e] = atomicAdd(&cnt4[s * N_ + dst[e]], 1);
    }
  } else {
    for (int idx = threadIdx.x; idx < 1152; idx += 256) {
      const float* A; const float* V; int i;
      if (idx < 64)       { i = idx;       A = We1; V = ae1; }
      else if (idx < 128) { i = idx - 64;  A = We2; V = ae2; }
      else if (idx < 384) { i = idx - 128; A = W1;  V = as1; }
      else if (idx < 640) { i = idx - 384; A = W1;  V = ad1; }
      else if (idx < 896) { i = idx - 640; A = W2;  V = as2; }
      else                { i = idx - 896; A = W2;  V = ad2; }
      int k = i >> 3, h = i & 7;
      float s = 0.f;
      for (int c = 0; c < FIN; ++c)
        s = fmaf(A[k * HC + h * FIN + c], V[h * FIN + c], s);
      M[idx] = s;
    }
    // fragment-ordered bf16 W1/W2 (16 tiles x 64 lanes x 8)
    for (int idx = threadIdx.x; idx < 8192; idx += 256) {
      int j = idx & 7, lane = (idx >> 3) & 63, tile = idx >> 9;
      int seg = lane >> 4, row = lane & 15;
      int hh = tile >> 1, n2 = tile & 1;
      int k = seg * 8 + j, col = hh * 32 + n2 * 16 + row;
      w1frag[idx] = __float2bfloat16(W1[k * HC + col]);
      w2frag[idx] = __float2bfloat16(W2[k * HC + col]);
    }
    // fragment-ordered bf16 lin1W (16 tiles)
    for (int idx = threadIdx.x; idx < 8192; idx += 256) {
      int j = idx & 7, lane = (idx >> 3) & 63, tl = idx >> 9;
      int seg = lane >> 4, row = lane & 15;
      int ct = tl >> 3, w_ = (tl >> 1) & 3, step = tl & 1;
      int krow = w_ * 64 + step * 32 + seg * 8 + j;
      w1linf[idx] = __float2bfloat16(lin1W[krow * 32 + ct * 16 + row]);
    }
    // fragment-ordered bf16 lin5W (8 tiles, cols 8..15 zero-padded)
    for (int idx = threadIdx.x; idx < 4096; idx += 256) {
      int j = idx & 7, lane = (idx >> 3) & 63, tl = idx >> 9;
      int seg = lane >> 4, row = lane & 15;
      int w_ = tl >> 1, step = tl & 1;
      int krow = w_ * 64 + step * 32 + seg * 8 + j;
      w2linf[idx] = (row < 8) ? __float2bfloat16(lin5W[krow * 8 + row])
                              : __float2bfloat16(0.f);
    }
  }
}

// scan step 1: per-256-tile inclusive prefix over TOTAL degree (4 shadows summed)
__global__ __launch_bounds__(256) void
scan_partial(const int* __restrict__ cnt4, int* __restrict__ tmp,
             int* __restrict__ bsum, int N_) {
  __shared__ int part[256];
  int t = threadIdx.x, i = blockIdx.x * 256 + t;
  int v = 0;
  if (i < N_) {
    v = cnt4[i] + cnt4[N_ + i] + cnt4[2 * N_ + i] + cnt4[3 * N_ + i];
  }
  part[t] = v;
  __syncthreads();
#pragma unroll
  for (int off = 1; off < 256; off <<= 1) {
    int u = (t >= off) ? part[t - off] : 0;
    __syncthreads();
    part[t] += u;
    __syncthreads();
  }
  if (i < N_) tmp[i] = part[t];
  if (t == 255) bsum[blockIdx.x] = part[255];
}

// scan step 2 (fused): block reduces bsum[0..bid); rowptr[i] = exclusive prefix;
// combined[s][i] = rowptr[i] + sum_{s'<s} cnt4[s'][i]  (scatter base per shadow).
__global__ __launch_bounds__(256) void
scan_final(const int* __restrict__ cnt4, const int* __restrict__ tmp,
           const int* __restrict__ bsum, int* __restrict__ rowptr,
           int* __restrict__ combined, int N_, int E_, int NB) {
  __shared__ int red[256];
  int t = threadIdx.x, b = blockIdx.x;
  int acc = 0;
  for (int j = t; j < b; j += 256) acc += bsum[j];
  red[t] = acc;
  __syncthreads();
#pragma unroll
  for (int off = 128; off > 0; off >>= 1) {
    if (t < off) red[t] += red[t + off];
    __syncthreads();
  }
  int boff = red[0];
  int i = b * 256 + t;
  if (i < N_) {
    int c0 = cnt4[i], c1 = cnt4[N_ + i], c2 = cnt4[2 * N_ + i], c3 = cnt4[3 * N_ + i];
    int tot = c0 + c1 + c2 + c3;
    int ex = boff + tmp[i] - tot;
    rowptr[i] = ex;
    combined[i]          = ex;
    combined[N_ + i]     = ex + c0;
    combined[2 * N_ + i] = ex + c0 + c1;
    combined[3 * N_ + i] = ex + c0 + c1 + c2;
  }
  if (i == 0) rowptr[N_] = E_;
}

// scatter-lite (no atomics, ONE 8B scattered write/edge) + fused layer-1 prep.
__global__ __launch_bounds__(256) void
scatter_prep_kernel(const int* __restrict__ src, const int* __restrict__ dst,
                    const int* __restrict__ combined, const int* __restrict__ ord,
                    int2* __restrict__ se,
                    const float* __restrict__ M,
                    const float* __restrict__ emb, const int* __restrict__ node_ids,
                    bf16* __restrict__ xq, float* __restrict__ alsrc,
                    float* __restrict__ aldst,
                    int E_, int N_, int eb) {
  __shared__ float xs[8][33];
  int t = threadIdx.x;
  if (blockIdx.x < (unsigned)eb) {
    int e = blockIdx.x * 256 + t;
    if (e < E_) {
      int s = e & (NSH - 1);
      int pos = combined[s * N_ + dst[e]] + ord[e];
      se[pos] = make_int2(src[e], e);   // single 8B scattered write
    }
  } else {
    const float* P = M + 128;
    int n0 = (blockIdx.x - eb) * 8;
    int nl = t >> 5, c = t & 31;
    int n = n0 + nl;
    if (n < N_) {
      float v = emb[(size_t)node_ids[n] * FIN + c];
      xq[(size_t)n * FIN + c] = __float2bfloat16(v);
      xs[nl][c] = v;
    }
    __syncthreads();
    if (t < 64) {
      int nl2 = t >> 3, h = t & 7;
      int n2 = n0 + nl2;
      if (n2 < N_) {
        float sa = 0.f, sd = 0.f;
#pragma unroll
        for (int k = 0; k < FIN; ++k) {
          float x = xs[nl2][k];
          sa = fmaf(x, P[k * 8 + h], sa);
          sd = fmaf(x, P[256 + k * 8 + h], sd);
        }
        alsrc[(size_t)n2 * NH + h] = sa;
        aldst[(size_t)n2 * NH + h] = sd;
      }
    }
  }
}

// pos-order pass: gather edge_attr[e] ONCE (random), fold with M, write
// srcs + per-layer packed bf16 records COALESCED (16B each layer).
__global__ __launch_bounds__(256) void
alepk_build_kernel(const int2* __restrict__ se, const float* __restrict__ edge_attr,
                   const float* __restrict__ M,
                   int* __restrict__ srcs, unsigned int* __restrict__ ale1pk,
                   unsigned int* __restrict__ ale2pk, int E_) {
  __shared__ float Msh[128];
  int t = threadIdx.x;
  if (t < 128) Msh[t] = M[t];
  __syncthreads();
  int pos = blockIdx.x * 256 + t;
  if (pos >= E_) return;
  int2 s2 = se[pos];
  srcs[pos] = s2.x;
  int e = s2.y;
  const float4* ep = (const float4*)(edge_attr + (size_t)e * NH);
  float4 a0 = ep[0], a1 = ep[1];
  float ea[8] = {a0.x, a0.y, a0.z, a0.w, a1.x, a1.y, a1.z, a1.w};
  float o1[8], o2[8];
#pragma unroll
  for (int h = 0; h < 8; ++h) { o1[h] = 0.f; o2[h] = 0.f; }
#pragma unroll
  for (int k = 0; k < 8; ++k) {
    float x = ea[k];
#pragma unroll
    for (int h = 0; h < 8; ++h) {
      o1[h] = fmaf(x, Msh[k * 8 + h], o1[h]);
      o2[h] = fmaf(x, Msh[64 + k * 8 + h], o2[h]);
    }
  }
  uint4 r0 = make_uint4(pk2(o1[0], o1[1]), pk2(o1[2], o1[3]),
                        pk2(o1[4], o1[5]), pk2(o1[6], o1[7]));
  uint4 r1 = make_uint4(pk2(o2[0], o2[1]), pk2(o2[2], o2[3]),
                        pk2(o2[4], o2[5]), pk2(o2[6], o2[7]));
  *(uint4*)(ale1pk + (size_t)pos * 4) = r0;
  *(uint4*)(ale2pk + (size_t)pos * 4) = r1;
}

// ---- fused agg: BARRIER-FREE main loop + double-MFMA epilogue (R14, verified)
template <int K, int LOG2K, bool LOGITS>
__global__ __launch_bounds__(256, 6) void
agg_kernel(const int* __restrict__ rowptr, const int* __restrict__ srcs,
           const bf16* __restrict__ ale,
           const float* __restrict__ alsrc, const float* __restrict__ aldst,
           const bf16* __restrict__ xq,
           const bf16* __restrict__ Wfrag, const float* __restrict__ b,
           const bf16* __restrict__ Wlinf, const float* __restrict__ blin,
           float* __restrict__ xoutf, bf16* __restrict__ xqn,
           const float* __restrict__ Pn,
           float* __restrict__ alsrcn, float* __restrict__ aldstn, int N_) {
  __shared__ __align__(16) char smem[17408];
  unsigned int* xsu = (unsigned int*)smem;
  float* wsf   = (float*)(smem + 8192);
  float* ald_s = (float*)(smem + 12288);
  float* red   = (float*)smem;
  float* xrow  = (float*)(smem + 16384);

  int t = threadIdx.x;
  int n0 = blockIdx.x * GROUP;
  int w = t >> 6, l = t & 63, h = l >> 3, q = l & 7;

  unsigned int* xw  = xsu + w * 512;
  float*        wsw = wsf + w * 256;
  char* xwb = smem + w * 2048;

  int nA = n0 + w * 2;
  int e0  = rowptr[(nA     <= N_) ? nA     : N_];
  int e1  = rowptr[(nA + 1 <= N_) ? nA + 1 : N_];
  int e2g = rowptr[(nA + 2 <= N_) ? nA + 2 : N_];

  if (t < GROUP * NH) {
    int nn = n0 + (t >> 3);
    ald_s[t] = (nn < N_) ? aldst[(size_t)nn * NH + (t & 7)] : 0.f;
  }
  __syncthreads();

  float4 acc0 = make_float4(0.f, 0.f, 0.f, 0.f);
  float4 acc1 = make_float4(0.f, 0.f, 0.f, 0.f);
  float dn0 = 0.f, dn1 = 0.f;

  for (int cbeg = e0; cbeg < e2g; cbeg += CAPW) {
    int clen = e2g - cbeg; if (clen > CAPW) clen = CAPW;

    // stage x rows: 2 passes of 16 edges via global_load_lds (16B/lane)
    {
      int el0 = (l >> 2);
      int coff = (l & 3);
      int ec0 = el0 < clen - 1 ? el0 : clen - 1;
      {
        int s = srcs[cbeg + ec0];
        const bf16* gp = xq + (size_t)s * FIN + coff * 8;
        __builtin_amdgcn_global_load_lds(
            (const __attribute__((address_space(1))) void*)gp,
            (__attribute__((address_space(3))) void*)xwb, 16, 0, 0);
      }
      if (clen > 16) {
        int el1 = 16 + el0;
        int ec1 = el1 < clen - 1 ? el1 : clen - 1;
        int s = srcs[cbeg + ec1];
        const bf16* gp = xq + (size_t)s * FIN + coff * 8;
        __builtin_amdgcn_global_load_lds(
            (const __attribute__((address_space(1))) void*)gp,
            (__attribute__((address_space(3))) void*)(xwb + 1024), 16, 0, 0);
      }
    }
    // stage exp(alpha): 2 lanes/edge
    {
      int e2 = l >> 1, half = l & 1;
      if (e2 < clen) {
        int j = cbeg + e2;
        int ii = (j >= e1) ? 1 : 0;
        int sn = srcs[j];
        uint2 ue  = *(const uint2*)(ale + (size_t)j * 8 + half * 4);
        float4 as4 = *(const float4*)(alsrc + (size_t)sn * NH + half * 4);
        float4 ad4 = *(const float4*)&ald_s[(w * 2 + ii) * 8 + half * 4];
        float a0f = blo(ue.x) + as4.x + ad4.x; a0f = (a0f >= 0.f) ? a0f : 0.2f * a0f;
        float a1f = bhi(ue.x) + as4.y + ad4.y; a1f = (a1f >= 0.f) ? a1f : 0.2f * a1f;
        float a2f = blo(ue.y) + as4.z + ad4.z; a2f = (a2f >= 0.f) ? a2f : 0.2f * a2f;
        float a3f = bhi(ue.y) + as4.w + ad4.w; a3f = (a3f >= 0.f) ? a3f : 0.2f * a3f;
        *(float4*)&wsw[e2 * 8 + half * 4] =
            make_float4(__expf(a0f), __expf(a1f), __expf(a2f), __expf(a3f));
      }
    }
    asm volatile("s_waitcnt vmcnt(0) lgkmcnt(0)" ::: "memory");

    int hA = e1 - cbeg; if (hA < 0) hA = 0; if (hA > clen) hA = clen;
#pragma unroll 4
    for (int le = 0; le < hA; ++le) {
      float wv = wsw[le * 8 + h];
      uint2 u = *(const uint2*)&xw[le * 16 + q * 2];
      acc0.x = fmaf(blo(u.x), wv, acc0.x);
      acc0.y = fmaf(bhi(u.x), wv, acc0.y);
      acc0.z = fmaf(blo(u.y), wv, acc0.z);
      acc0.w = fmaf(bhi(u.y), wv, acc0.w);
      dn0 += wv;
    }
#pragma unroll 4
    for (int le = hA; le < clen; ++le) {
      float wv = wsw[le * 8 + h];
      uint2 u = *(const uint2*)&xw[le * 16 + q * 2];
      acc1.x = fmaf(blo(u.x), wv, acc1.x);
      acc1.y = fmaf(bhi(u.x), wv, acc1.y);
      acc1.z = fmaf(blo(u.y), wv, acc1.z);
      acc1.w = fmaf(bhi(u.y), wv, acc1.w);
      dn1 += wv;
    }
    asm volatile("s_waitcnt lgkmcnt(0)" ::: "memory");
  }

  // normalize + write z XOR-swizzled (float4 #f of node n at n*1024+((f^n)&63)*16)
  float rd0 = 1.0f / (dn0 + 1e-16f);
  float rd1 = 1.0f / (dn1 + 1e-16f);
  {
    int na0 = w * 2, na1 = w * 2 + 1;
    *(float4*)(smem + na0 * 1024 + ((l ^ na0) & 63) * 16) =
        make_float4(acc0.x * rd0, acc0.y * rd0, acc0.z * rd0, acc0.w * rd0);
    *(float4*)(smem + na1 * 1024 + ((l ^ na1) & 63) * 16) =
        make_float4(acc1.x * rd1, acc1.y * rd1, acc1.z * rd1, acc1.w * rd1);
  }
  __syncthreads();

  typedef __attribute__((ext_vector_type(8))) short short8v;
  typedef __attribute__((ext_vector_type(4))) float f32x4v;
  int lo = l & 15, seg = l >> 4;

  // (a) g = relu(z @ W + b) via MFMA; gs stored swizzled at smem+8192
  {
#pragma unroll
    for (int hh2 = 0; hh2 < 2; ++hh2) {
      int hh = w * 2 + hh2;
      short8v af;
      if (lo < GROUP) {
        int f0 = hh * 8 + seg * 2;
        float4 za = *(const float4*)(smem + lo * 1024 + ((f0 ^ lo) & 63) * 16);
        float4 zb = *(const float4*)(smem + lo * 1024 + (((f0 + 1) ^ lo) & 63) * 16);
        af[0] = bfs(za.x); af[1] = bfs(za.y); af[2] = bfs(za.z); af[3] = bfs(za.w);
        af[4] = bfs(zb.x); af[5] = bfs(zb.y); af[6] = bfs(zb.z); af[7] = bfs(zb.w);
      } else {
#pragma unroll
        for (int j = 0; j < 8; ++j) af[j] = 0;
      }
#pragma unroll
      for (int n2 = 0; n2 < 2; ++n2) {
        int tile = hh * 2 + n2;
        uint4 bw = *(const uint4*)(Wfrag + (size_t)tile * 512 + l * 8);
        short8v bfv;
        __builtin_memcpy(&bfv, &bw, 16);
        f32x4v d = {0.f, 0.f, 0.f, 0.f};
        d = __builtin_amdgcn_mfma_f32_16x16x32_bf16(af, bfv, d, 0, 0, 0);
#pragma unroll
        for (int r = 0; r < 4; ++r) {
          int rd = seg * 4 + r;
          if (rd < GROUP) {
            int tc = hh * 32 + n2 * 16 + lo;
            float gv = d[r] + b[tc];
            gv = (gv > 0.f) ? gv : 0.f;
            *(float*)(smem + 8192 + rd * 1024 +
                      (((tc >> 2) ^ rd) & 63) * 16 + (tc & 3) * 4) = gv;
          }
        }
      }
    }
  }
  __syncthreads();   // all z reads done -> red (aliases z) safe; gs wave-local

  // (b) lin via MFMA: wave w k-slice [64w,64w+64) (its own gs cols)
  {
    short8v af0, af1;
    if (lo < GROUP) {
      int f0 = 16 * w + 2 * seg;
      float4 ga = *(const float4*)(smem + 8192 + lo * 1024 + ((f0 ^ lo) & 63) * 16);
      float4 gb = *(const float4*)(smem + 8192 + lo * 1024 + (((f0 + 1) ^ lo) & 63) * 16);
      int f1 = 16 * w + 8 + 2 * seg;
      float4 gc = *(const float4*)(smem + 8192 + lo * 1024 + ((f1 ^ lo) & 63) * 16);
      float4 gd = *(const float4*)(smem + 8192 + lo * 1024 + (((f1 + 1) ^ lo) & 63) * 16);
      af0[0] = bfs(ga.x); af0[1] = bfs(ga.y); af0[2] = bfs(ga.z); af0[3] = bfs(ga.w);
      af0[4] = bfs(gb.x); af0[5] = bfs(gb.y); af0[6] = bfs(gb.z); af0[7] = bfs(gb.w);
      af1[0] = bfs(gc.x); af1[1] = bfs(gc.y); af1[2] = bfs(gc.z); af1[3] = bfs(gc.w);
      af1[4] = bfs(gd.x); af1[5] = bfs(gd.y); af1[6] = bfs(gd.z); af1[7] = bfs(gd.w);
    } else {
#pragma unroll
      for (int j = 0; j < 8; ++j) { af0[j] = 0; af1[j] = 0; }
    }
#pragma unroll
    for (int ct = 0; ct < (LOGITS ? 2 : 1); ++ct) {
      int tl = LOGITS ? ((ct * 4 + w) * 2) : (w * 2);
      uint4 b0 = *(const uint4*)(Wlinf + (size_t)tl * 512 + l * 8);
      uint4 b1 = *(const uint4*)(Wlinf + (size_t)(tl + 1) * 512 + l * 8);
      short8v bv0, bv1;
      __builtin_memcpy(&bv0, &b0, 16);
      __builtin_memcpy(&bv1, &b1, 16);
      f32x4v d = {0.f, 0.f, 0.f, 0.f};
      d = __builtin_amdgcn_mfma_f32_16x16x32_bf16(af0, bv0, d, 0, 0, 0);
      d = __builtin_amdgcn_mfma_f32_16x16x32_bf16(af1, bv1, d, 0, 0, 0);
      int base = (LOGITS ? (ct * 4 + w) : w) * 256;
#pragma unroll
      for (int r = 0; r < 4; ++r)
        red[base + (seg * 4 + r) * 16 + lo] = d[r];
    }
  }
  __syncthreads();

  // combine partials (+blin) -> outputs
  if (LOGITS) {
    {
      int i = t >> 5, kk = t & 31;
      int ct = kk >> 4, n = kk & 15;
      float s = blin[kk]
              + red[(ct * 4 + 0) * 256 + i * 16 + n]
              + red[(ct * 4 + 1) * 256 + i * 16 + n]
              + red[(ct * 4 + 2) * 256 + i * 16 + n]
              + red[(ct * 4 + 3) * 256 + i * 16 + n];
      int nn = n0 + i;
      if (nn < N_) xqn[(size_t)nn * FIN + kk] = __float2bfloat16(s);
      xrow[t] = s;
    }
    __syncthreads();
    if (t < GROUP * NH) {
      int i = t >> 3, hh = t & 7;
      int nn = n0 + i;
      if (nn < N_) {
        float sa = 0.f, sd = 0.f;
#pragma unroll
        for (int k2 = 0; k2 < FIN; ++k2) {
          float x = xrow[i * 32 + k2];
          sa = fmaf(x, Pn[k2 * 8 + hh], sa);
          sd = fmaf(x, Pn[256 + k2 * 8 + hh], sd);
        }
        alsrcn[(size_t)nn * NH + hh] = sa;
        aldstn[(size_t)nn * NH + hh] = sd;
      }
    }
  } else {
    if (t < GROUP * K) {
      int i = t >> LOG2K, kk = t & (K - 1);
      float s = blin[kk]
              + red[0 * 256 + i * 16 + kk]
              + red[1 * 256 + i * 16 + kk]
              + red[2 * 256 + i * 16 + kk]
              + red[3 * 256 + i * 16 + kk];
      int nn = n0 + i;
      if (nn < N_) xoutf[(size_t)nn * K + kk] = s;
    }
  }
}

// ---------------- classifier: sigmoid(sum(fu*fm)) ----------------------------
__global__ void clf_kernel(const int* __restrict__ eli, const float* __restrict__ ela,
                           const float* __restrict__ x2, const float* __restrict__ clfW,
                           const float* __restrict__ clfb, float* __restrict__ out, int L_) {
  int i = blockIdx.x * blockDim.x + threadIdx.x;
  if (i >= L_) return;
  int u = eli[i], m = eli[L_ + i];
  const float4* xup = (const float4*)(x2 + (size_t)u * NH);
  const float4* xmp = (const float4*)(x2 + (size_t)m * NH);
  const float4* eap = (const float4*)(ela + (size_t)i * NH);
  float4 xu0 = xup[0], xu1 = xup[1];
  float4 xm0 = xmp[0], xm1 = xmp[1];
  float4 el0 = eap[0], el1 = eap[1];
  float xu[NH] = {xu0.x, xu0.y, xu0.z, xu0.w, xu1.x, xu1.y, xu1.z, xu1.w};
  float xm[NH] = {xm0.x, xm0.y, xm0.z, xm0.w, xm1.x, xm1.y, xm1.z, xm1.w};
  float el[NH] = {el0.x, el0.y, el0.z, el0.w, el1.x, el1.y, el1.z, el1.w};
  float fu[NH];
#pragma unroll
  for (int kk = 0; kk < NH; ++kk) fu[kk] = clfb[kk];
#pragma unroll
  for (int j = 0; j < NH; ++j) {
#pragma unroll
    for (int kk = 0; kk < NH; ++kk) fu[kk] = fmaf(xu[j], clfW[j * NH + kk], fu[kk]);
  }
#pragma unroll
  for (int j = 0; j < NH; ++j) {
#pragma unroll
    for (int kk = 0; kk < NH; ++kk) fu[kk] = fmaf(el[j], clfW[(NH + j) * NH + kk], fu[kk]);
  }
  float dot = 0.f;
#pragma unroll
  for (int kk = 0; kk < NH; ++kk) dot += fu[kk] * xm[kk];
  out[i] = 1.f / (1.f + __expf(-dot));
}

extern "C" void kernel_launch(void* const* d_in, const int* in_sizes, int n_in,
                              void* d_out, int out_size, void* d_ws, size_t ws_size,
                              hipStream_t stream) {
  const int* node_ids   = (const int*)d_in[0];
  const int* edge_index = (const int*)d_in[1];
  const int* eli        = (const int*)d_in[2];
  const float* edge_attr = (const float*)d_in[4];
  const float* ela       = (const float*)d_in[5];
  const float* emb       = (const float*)d_in[6];
  const float* W1     = (const float*)d_in[7];
  const float* a_src1 = (const float*)d_in[8];
  const float* a_dst1 = (const float*)d_in[9];
  const float* We1    = (const float*)d_in[10];
  const float* a_e1   = (const float*)d_in[11];
  const float* b1     = (const float*)d_in[12];
  const float* lin1W  = (const float*)d_in[13];
  const float* lin1b  = (const float*)d_in[14];
  const float* W2     = (const float*)d_in[15];
  const float* a_src2 = (const float*)d_in[16];
  const float* a_dst2 = (const float*)d_in[17];
  const float* We2    = (const float*)d_in[18];
  const float* a_e2   = (const float*)d_in[19];
  const float* b2     = (const float*)d_in[20];
  const float* lin5W  = (const float*)d_in[21];
  const float* lin5b  = (const float*)d_in[22];
  const float* clfW   = (const float*)d_in[23];
  const float* clfb   = (const float*)d_in[24];

  const int N_ = in_sizes[0];
  const int E_ = in_sizes[1] / 2;
  const int L_ = in_sizes[2] / 2;
  const int* src  = edge_index;
  const int* dstp = edge_index + E_;

  char* p = (char*)d_ws;
  auto carve = [&](size_t bytes) -> char* {
    char* r = p;
    p += (bytes + 255) & ~(size_t)255;
    return r;
  };
  bf16*  xq1     = (bf16*)carve((size_t)N_ * FIN * 2);
  bf16*  xq2     = (bf16*)carve((size_t)N_ * FIN * 2);
  unsigned int* ale1pk = (unsigned int*)carve((size_t)E_ * 16);
  unsigned int* ale2pk = (unsigned int*)carve((size_t)E_ * 16);
  float* alsrc1  = (float*)carve((size_t)N_ * NH * 4);
  float* aldst1  = (float*)carve((size_t)N_ * NH * 4);
  float* alsrc2  = (float*)carve((size_t)N_ * NH * 4);
  float* aldst2  = (float*)carve((size_t)N_ * NH * 4);
  float* x2b     = (float*)carve((size_t)N_ * NH * 4);
  float* Mbuf    = (float*)carve(1152 * 4);
  bf16*  w1frag  = (bf16*)carve(8192 * 2);
  bf16*  w2frag  = (bf16*)carve(8192 * 2);
  bf16*  w1linf  = (bf16*)carve(8192 * 2);
  bf16*  w2linf  = (bf16*)carve(4096 * 2);
  int*   cnt4    = (int*)carve((size_t)NSH * N_ * 4);
  int*   rowptr  = (int*)carve((size_t)(N_ + 1) * 4);
  int*   combined= (int*)carve((size_t)NSH * N_ * 4);
  int*   stmp    = (int*)carve((size_t)N_ * 4);
  int*   bsum    = (int*)carve(1024 * 4);
  int*   srcs    = (int*)carve((size_t)E_ * 4);
  int*   ordb    = (int*)carve((size_t)E_ * 4);
  int2*  se      = (int2*)carve((size_t)E_ * 8);

  hipMemsetAsync(cnt4, 0, (size_t)NSH * N_ * 4, stream);
  int eb = (E_ + 255) / 256;
  int nb = (N_ + 255) / 256;
  int pb = (N_ + 7) / 8;
  count_fold_kernel<<<eb + 1, 256, 0, stream>>>(dstp, cnt4, ordb, E_, N_, eb,
                                                We1, a_e1, We2, a_e2,
                                                W1, a_src1, a_dst1,
                                                W2, a_src2, a_dst2,
                                                lin1W, lin5W, Mbuf,
                                                w1frag, w2frag, w1linf, w2linf);
  scan_partial<<<nb, 256, 0, stream>>>(cnt4, stmp, bsum, N_);
  scan_final<<<nb, 256, 0, stream>>>(cnt4, stmp, bsum, rowptr, combined, N_, E_, nb);
  scatter_prep_kernel<<<eb + pb, 256, 0, stream>>>(
      src, dstp, combined, ordb, se, Mbuf,
      emb, node_ids, xq1, alsrc1, aldst1, E_, N_, eb);
  alepk_build_kernel<<<eb, 256, 0, stream>>>(se, edge_attr, Mbuf, srcs,
                                             ale1pk, ale2pk, E_);

  int gb = (N_ + GROUP - 1) / GROUP;
  // ---- layer 1 (fully fused) ----
  agg_kernel<32, 5, true><<<gb, 256, 0, stream>>>(
      rowptr, srcs, (const bf16*)ale1pk, alsrc1, aldst1, xq1,
      w1frag, b1, w1linf, lin1b, nullptr, xq2, Mbuf + 640, alsrc2, aldst2, N_);

  // ---- layer 2 ----
  agg_kernel<8, 3, false><<<gb, 256, 0, stream>>>(
      rowptr, srcs, (const bf16*)ale2pk, alsrc2, aldst2, xq2,
      w2frag, b2, w2linf, lin5b, x2b, nullptr, nullptr, nullptr, nullptr, N_);

  // ---- classifier ----
  clf_kernel<<<(L_ + 255) / 256, 256, 0, stream>>>(eli, ela, x2b, clfW, clfb,
                                                   (float*)d_out, L_);
}